// Round 8
// 4776.735 us; speedup vs baseline: 1.0309x; 1.0309x over previous
//
#include <hip/hip_runtime.h>
#include <cstdint>
#include <cstddef>

// Problem constants
#define BB     8
#define DIMC   512
#define LL     4096
#define POSN   (BB*LL)        // 32768
#define NG     2
#define NQ     8
#define CS     1024
#define DG     256

// d_out layout (floats): q [8*512*4096] | indices [2*8*4096*8] | losses [16]
#define Q_OFF    0
#define IDX_OFF  16777216
#define LOSS_OFF 17301504

// d_ws layout (floats)
#define OFF_WFT   0               // [1536][512]
#define OFF_BF    786432          // [512]
#define OFF_C2    786944          // [16][1024]
#define OFF_QH    803328          // qh+ql: 2 x 16777216 f16 = 16777216 floats
#define OFF_CANDD 17580544        // [32768][8] float
#define OFF_CANDI 17842688        // [32768][8] int
#define OFF_LOSSP 18104832        // [16][1024]
#define OFF_PWH   18121216        // pwh+pwl: 2 x 262144 f16 = 262144 floats
// total 18383360 floats = 73.5 MB

typedef _Float16 f16;
typedef _Float16 f16x8 __attribute__((ext_vector_type(8)));
typedef _Float16 f16x4 __attribute__((ext_vector_type(4)));
typedef float f32x4 __attribute__((ext_vector_type(4)));

#define LO_SCALE      1024.f
#define LO_INV        (1.f/1024.f)
#define F16_MIN_NORM  6.103515625e-05f

struct f16pair { f16 h, l; };

// flush-proof fp16 hi/lo split (used ONLY on the post-linear path, never on
// anything that feeds the VQ argmin)
__device__ __forceinline__ f16pair split1(float v) {
    f16 hv = (f16)v;
    float hf = (float)hv;
    if (__builtin_fabsf(hf) < F16_MIN_NORM) { hv = (f16)0.f; hf = 0.f; }
    f16pair p;
    p.h = hv;
    p.l = (f16)((v - hf) * LO_SCALE);
    return p;
}

__device__ __forceinline__ void gload16(const void* g, void* l) {
    __builtin_amdgcn_global_load_lds(
        (const __attribute__((address_space(1))) void*)g,
        (__attribute__((address_space(3))) void*)l, 16, 0, 0);
}

// ---------------------------------------------------------------------------
// Fuse conv_enc weights with pre_w:  Wf_t[ik][dd] = sum_j cw[j][i][k]*prew[dd][j]
__global__ __launch_bounds__(256) void k_fuse_w(const float* __restrict__ cw,
                                               const float* __restrict__ prew,
                                               float* __restrict__ wft) {
    __shared__ __align__(16) float As[16][68];  // As[k][ik]
    __shared__ __align__(16) float Bs[16][68];  // Bs[k][dd]
    int bid = blockIdx.x;
    int mt = bid >> 3, nt = bid & 7;            // 24 x 8
    int m0 = mt * 64, n0 = nt * 64;
    int t = threadIdx.x, tx = t & 15, ty = t >> 4;
    float acc[4][4] = {};
    for (int k0 = 0; k0 < 512; k0 += 16) {
        for (int u = t; u < 16 * 64; u += 256) {
            int kk = u >> 6, mm = u & 63;
            As[kk][mm] = cw[(size_t)(k0 + kk) * 1536 + m0 + mm];
        }
        {
            int r = t >> 2, c4 = t & 3;
            float4 v = *(const float4*)&prew[(size_t)(n0 + r) * 512 + k0 + c4 * 4];
            Bs[c4 * 4 + 0][r] = v.x; Bs[c4 * 4 + 1][r] = v.y;
            Bs[c4 * 4 + 2][r] = v.z; Bs[c4 * 4 + 3][r] = v.w;
        }
        __syncthreads();
#pragma unroll
        for (int k = 0; k < 16; ++k) {
            float4 a = *(const float4*)&As[k][ty * 4];
            float4 b = *(const float4*)&Bs[k][tx * 4];
            float av[4] = {a.x, a.y, a.z, a.w}, bv[4] = {b.x, b.y, b.z, b.w};
#pragma unroll
            for (int i = 0; i < 4; ++i)
#pragma unroll
                for (int j = 0; j < 4; ++j) acc[i][j] += av[i] * bv[j];
        }
        __syncthreads();
    }
#pragma unroll
    for (int i = 0; i < 4; ++i) {
        float4 v = {acc[i][0], acc[i][1], acc[i][2], acc[i][3]};
        *(float4*)&wft[(size_t)(m0 + ty * 4 + i) * 512 + n0 + tx * 4] = v;
    }
}

// Fused bias: bf[dd] = preb[dd] + sum_j prew[dd][j]*ceb[j]
__global__ void k_bias(const float* __restrict__ prew, const float* __restrict__ preb,
                       const float* __restrict__ ceb, float* __restrict__ bf) {
    int dd = blockIdx.x * 256 + threadIdx.x;
    if (dd < 512) {
        float s = preb[dd];
        for (int j = 0; j < 512; ++j) s += prew[(size_t)dd * 512 + j] * ceb[j];
        bf[dd] = s;
    }
}

// c2[row] = sum_d cb[row][d]^2, row over [16][1024]
__global__ void k_c2(const float* __restrict__ cb, float* __restrict__ c2) {
    int wave = threadIdx.x >> 6, lane = threadIdx.x & 63;
    int row = blockIdx.x * 4 + wave;  // < 16384
    const float* r = cb + (size_t)row * 256;
    float4 v = *(const float4*)&r[lane * 4];
    float s = v.x * v.x + v.y * v.y + v.z * v.z + v.w * v.w;
#pragma unroll
    for (int m = 1; m < 64; m <<= 1) s += __shfl_xor(s, m);
    if (lane == 0) c2[row] = s;
}

// split post_w fp32 -> fp16 hi + scaled fp16 lo (post-linear operands only)
__global__ void k_split_pw(const float* __restrict__ pw, f16* __restrict__ ph,
                           f16* __restrict__ pl) {
    size_t i = ((size_t)blockIdx.x * 256 + threadIdx.x) * 4;
    float4 v = *(const float4*)&pw[i];
    f16x4 hv, lv;
    f16pair p0 = split1(v.x), p1 = split1(v.y), p2 = split1(v.z), p3 = split1(v.w);
    hv.x = p0.h; lv.x = p0.l;
    hv.y = p1.h; lv.y = p1.l;
    hv.z = p2.h; lv.z = p2.l;
    hv.w = p3.h; lv.w = p3.l;
    *(f16x4*)&ph[i] = hv;
    *(f16x4*)&pl[i] = lv;
}

// Fused conv1d(k=3) + pre-linear: BASELINE-VERBATIM fp32 (feeds the argmin)
__global__ __launch_bounds__(256) void k_conv(const float* __restrict__ x,
                                              const float* __restrict__ wft,
                                              const float* __restrict__ bf,
                                              float* __restrict__ h) {
    int bid = blockIdx.x;              // 4096 = dt(8) * b(8) * lt(64)
    int dt = bid >> 9;
    int rem = bid & 511;
    int bb = rem >> 6, lt = rem & 63;
    int l0 = lt * 64, d0 = dt * 64;
    int t = threadIdx.x, tx = t & 15, ty = t >> 4;
    __shared__ float Xs[8][68];
    __shared__ __align__(16) float Ws[24][64];
    float acc[4][4] = {};
    const float* xb = x + (size_t)bb * 512 * 4096;
    for (int i0 = 0; i0 < 512; i0 += 8) {
        for (int u = t; u < 8 * 66; u += 256) {
            int ii = u / 66, c = u % 66;
            int gl = l0 + c - 1;
            Xs[ii][c] = (gl >= 0 && gl < 4096) ? xb[(size_t)(i0 + ii) * 4096 + gl] : 0.f;
        }
        for (int u = t; u < 24 * 64; u += 256) {
            int r = u >> 6, c = u & 63;
            Ws[r][c] = wft[(size_t)(i0 * 3 + r) * 512 + d0 + c];
        }
        __syncthreads();
#pragma unroll
        for (int ii = 0; ii < 8; ++ii) {
            float a[6];
#pragma unroll
            for (int j = 0; j < 6; ++j) a[j] = Xs[ii][ty * 4 + j];
#pragma unroll
            for (int k = 0; k < 3; ++k) {
                float4 b = *(const float4*)&Ws[ii * 3 + k][tx * 4];
                float bv[4] = {b.x, b.y, b.z, b.w};
#pragma unroll
                for (int jl = 0; jl < 4; ++jl)
#pragma unroll
                    for (int jd = 0; jd < 4; ++jd) acc[jl][jd] += a[jl + k] * bv[jd];
            }
        }
        __syncthreads();
    }
    int posb = bb * 4096 + l0 + ty * 4;
    const float4 bias = *(const float4*)&bf[d0 + tx * 4];
#pragma unroll
    for (int jl = 0; jl < 4; ++jl) {
        float4 v = {acc[jl][0] + bias.x, acc[jl][1] + bias.y,
                    acc[jl][2] + bias.z, acc[jl][3] + bias.w};
        *(float4*)&h[(size_t)(posb + jl) * 512 + d0 + tx * 4] = v;
    }
}

// dots GEMM + per-tile argmin: BASELINE-VERBATIM fp32 (feeds the argmin)
__global__ __launch_bounds__(256) void k_dots(const float* __restrict__ hres,
                                              const float* __restrict__ cb,
                                              const float* __restrict__ c2,
                                              float* __restrict__ candd,
                                              int* __restrict__ candi,
                                              int q, int g) {
    __shared__ __align__(16) float As[16][132];
    __shared__ __align__(16) float Bs[16][132];
    __shared__ float Dd[16][128];
    __shared__ int   Di[16][128];
    int bid = blockIdx.x;             // 2048 = mt(256) * nt(8)
    int mt = bid >> 3, nt = bid & 7;
    int p0 = mt * 128, n0 = nt * 128;
    int t = threadIdx.x, pt = t & 15, ct = t >> 4;
    const float* cbq = cb + (size_t)(q * 2 + g) * 1024 * 256;
    const float* c2q = c2 + (q * 2 + g) * 1024;
    float acc[8][8] = {};
    for (int k0 = 0; k0 < 256; k0 += 16) {
        for (int u = t; u < 128 * 4; u += 256) {
            int r = u >> 2, c4 = u & 3;
            float4 v = *(const float4*)&hres[(size_t)(p0 + r) * 512 + g * 256 + k0 + c4 * 4];
            As[c4 * 4 + 0][r] = v.x; As[c4 * 4 + 1][r] = v.y;
            As[c4 * 4 + 2][r] = v.z; As[c4 * 4 + 3][r] = v.w;
        }
        for (int u = t; u < 128 * 4; u += 256) {
            int r = u >> 2, c4 = u & 3;
            float4 v = *(const float4*)&cbq[(size_t)(n0 + r) * 256 + k0 + c4 * 4];
            Bs[c4 * 4 + 0][r] = v.x; Bs[c4 * 4 + 1][r] = v.y;
            Bs[c4 * 4 + 2][r] = v.z; Bs[c4 * 4 + 3][r] = v.w;
        }
        __syncthreads();
#pragma unroll
        for (int k = 0; k < 16; ++k) {
            float4 a0 = *(const float4*)&As[k][pt * 8];
            float4 a1 = *(const float4*)&As[k][pt * 8 + 4];
            float4 b0 = *(const float4*)&Bs[k][ct * 8];
            float4 b1 = *(const float4*)&Bs[k][ct * 8 + 4];
            float av[8] = {a0.x, a0.y, a0.z, a0.w, a1.x, a1.y, a1.z, a1.w};
            float bv[8] = {b0.x, b0.y, b0.z, b0.w, b1.x, b1.y, b1.z, b1.w};
#pragma unroll
            for (int i = 0; i < 8; ++i)
#pragma unroll
                for (int j = 0; j < 8; ++j) acc[i][j] += av[i] * bv[j];
        }
        __syncthreads();
    }
    // per-thread argmin over its 8 codes (ascending c; strict < keeps first occurrence)
#pragma unroll
    for (int i = 0; i < 8; ++i) {
        float bd = 1e30f; int bi = 0x7fffffff;
#pragma unroll
        for (int j = 0; j < 8; ++j) {
            int c = n0 + ct * 8 + j;
            float d = c2q[c] - 2.f * acc[i][j];
            if (d < bd) { bd = d; bi = c; }
        }
        Dd[ct][pt * 8 + i] = bd;
        Di[ct][pt * 8 + i] = bi;
    }
    __syncthreads();
    if (t < 128) {
        float bd = Dd[0][t]; int bi = Di[0][t];
#pragma unroll
        for (int j = 1; j < 16; ++j) {
            float d = Dd[j][t]; int i2 = Di[j][t];
            if (d < bd || (d == bd && i2 < bi)) { bd = d; bi = i2; }
        }
        candd[(size_t)(p0 + t) * 8 + nt] = bd;
        candi[(size_t)(p0 + t) * 8 + nt] = bi;
    }
}

// finalize one VQ step: BASELINE-VERBATIM selection/update, qout block removed
__global__ __launch_bounds__(256) void k_fin(float* __restrict__ hres,
                                             const float* __restrict__ cb,
                                             const float* __restrict__ candd,
                                             const int* __restrict__ candi,
                                             float* __restrict__ lossp,
                                             float* __restrict__ idx_out,
                                             int q, int g) {
    int t = threadIdx.x, wave = t >> 6, lane = t & 63;
    const float* cbq = cb + (size_t)(q * 2 + g) * 1024 * 256;
    float lsum = 0.f;
    int pbase = blockIdx.x * 32 + wave * 8;   // grid 1024, 32 pos/block
    for (int i = 0; i < 8; ++i) {
        int pos = pbase + i;
        float bd; int bi;
        if (lane < 8) { bd = candd[(size_t)pos * 8 + lane]; bi = candi[(size_t)pos * 8 + lane]; }
        else          { bd = 1e30f; bi = 0x7fffffff; }
#pragma unroll
        for (int m = 1; m < 8; m <<= 1) {
            float d2 = __shfl_xor(bd, m);
            int   i2 = __shfl_xor(bi, m);
            if (d2 < bd || (d2 == bd && i2 < bi)) { bd = d2; bi = i2; }
        }
        int idx = __shfl(bi, 0);
        float4 cv = *(const float4*)&cbq[(size_t)idx * 256 + lane * 4];
        size_t ro = (size_t)pos * 512 + g * 256 + lane * 4;
        float4 rv = *(const float4*)&hres[ro];
        float4 rn = {rv.x - cv.x, rv.y - cv.y, rv.z - cv.z, rv.w - cv.w};
        *(float4*)&hres[ro] = rn;
        lsum += rn.x * rn.x + rn.y * rn.y + rn.z * rn.z + rn.w * rn.w;
        if (lane == 0)
            idx_out[(size_t)(g * 32768 + pos) * 8 + q] = (float)idx;
    }
#pragma unroll
    for (int m = 1; m < 64; m <<= 1) lsum += __shfl_xor(lsum, m);
    __shared__ float ls[4];
    if (lane == 0) ls[wave] = lsum;
    __syncthreads();
    if (t == 0) lossp[(size_t)(g * 8 + q) * 1024 + blockIdx.x] = ls[0] + ls[1] + ls[2] + ls[3];
}

// qout[pos][g*256..] = sum_q cb[q][g][idx[q]]; written as f16 hi/lo split for k_post
__global__ __launch_bounds__(256) void k_qsum2(const float* __restrict__ idxf,
                                               const float* __restrict__ cb,
                                               f16* __restrict__ qh,
                                               f16* __restrict__ ql) {
    int t = threadIdx.x, w = t >> 6, lane = t & 63;
    int pair = blockIdx.x * 4 + w;       // 65536 pairs
    int g = pair & 1, pos = pair >> 1;
    const float* ip = idxf + ((size_t)g * 32768 + pos) * 8;
    float4 s = {0.f, 0.f, 0.f, 0.f};
    for (int qq = 0; qq < 8; ++qq) {
        int ii = (int)ip[qq];
        const float* rowp = cb + ((size_t)(qq * 2 + g) * 1024 + ii) * 256;
        float4 v = *(const float4*)&rowp[lane * 4];
        s.x += v.x; s.y += v.y; s.z += v.z; s.w += v.w;
    }
    f16x4 hv, lv;
    f16pair p0 = split1(s.x), p1 = split1(s.y), p2 = split1(s.z), p3 = split1(s.w);
    hv.x = p0.h; lv.x = p0.l;
    hv.y = p1.h; lv.y = p1.l;
    hv.z = p2.h; lv.z = p2.l;
    hv.w = p3.h; lv.w = p3.l;
    size_t o = (size_t)pos * 512 + g * 256 + lane * 4;
    *(f16x4*)&qh[o] = hv;
    *(f16x4*)&ql[o] = lv;
}

// post-linear via MFMA fp16x3 (output tolerance ~1e-2; fp16x3 error ~1e-7).
// Grid 1024 = mt(256) x nt(4). Tile 128 pos x 128 dd, K=512 in chunks of 32.
// Transposed store is free: acc[mi][nj] f32x4 = 4 consecutive l for fixed dd.
__global__ __launch_bounds__(256) void k_post_mfma(const f16* __restrict__ qh,
                                                   const f16* __restrict__ ql,
                                                   const f16* __restrict__ pwh,
                                                   const f16* __restrict__ pwl,
                                                   const float* __restrict__ pb,
                                                   float* __restrict__ out) {
    __shared__ __align__(16) f16 Ah[4096], Al[4096], Bh[4096], Bl[4096];
    int bid = blockIdx.x;
    int mt = bid >> 2, nt = bid & 3;
    int p0 = mt << 7, d0 = nt << 7;
    int t = threadIdx.x, w = t >> 6, lane = t & 63;
    int wm = (w >> 1) * 64, wn = (w & 1) * 64;
    const f16* gA;
    f16* lA;
    {
        const f16* a0 = qh + (size_t)p0 * 512;
        const f16* a1 = ql + (size_t)p0 * 512;
        const f16* b0 = pwh + (size_t)d0 * 512;
        const f16* b1 = pwl + (size_t)d0 * 512;
        gA = (w == 0) ? a0 : (w == 1) ? a1 : (w == 2) ? b0 : b1;
        lA = (w == 0) ? Ah : (w == 1) ? Al : (w == 2) ? Bh : Bl;
    }
    f32x4 acc[4][4] = {};    // hi.hi
    f32x4 acc2[4][4] = {};   // hi.lo' + lo'.hi  (1024x true value)
    int lr = lane & 15, kq = lane >> 4;
    for (int k0 = 0; k0 < 512; k0 += 32) {
#pragma unroll
        for (int u = 0; u < 8; ++u) {
            int kb = u >> 1, hf = u & 1;
            gload16(gA + (size_t)(hf * 64 + lane) * 512 + k0 + kb * 8,
                    lA + kb * 1024 + hf * 512);
        }
        __syncthreads();
        f16x8 a_h[4], a_l[4], b_h[4], b_l[4];
#pragma unroll
        for (int i = 0; i < 4; ++i) {
            int ao = kq * 1024 + (wm + i * 16 + lr) * 8;
            int bo = kq * 1024 + (wn + i * 16 + lr) * 8;
            a_h[i] = *(const f16x8*)&Ah[ao];
            a_l[i] = *(const f16x8*)&Al[ao];
            b_h[i] = *(const f16x8*)&Bh[bo];
            b_l[i] = *(const f16x8*)&Bl[bo];
        }
#pragma unroll
        for (int i = 0; i < 4; ++i)
#pragma unroll
            for (int j = 0; j < 4; ++j) {
                acc[i][j]  = __builtin_amdgcn_mfma_f32_16x16x32_f16(a_h[i], b_h[j], acc[i][j], 0, 0, 0);
                acc2[i][j] = __builtin_amdgcn_mfma_f32_16x16x32_f16(a_h[i], b_l[j], acc2[i][j], 0, 0, 0);
                acc2[i][j] = __builtin_amdgcn_mfma_f32_16x16x32_f16(a_l[i], b_h[j], acc2[i][j], 0, 0, 0);
            }
        __syncthreads();
    }
    // C/D: col = lane&15 (dd), row = (lane>>4)*4 + rg (pos). Store f32x4 over rg.
    int bb = p0 >> 12, l0 = p0 & 4095;
#pragma unroll
    for (int nj = 0; nj < 4; ++nj) {
        int dd = d0 + wn + nj * 16 + lr;
        float bias = pb[dd];
        float* orow = out + ((size_t)bb * 512 + dd) * 4096 + l0 + wm + kq * 4;
#pragma unroll
        for (int mi = 0; mi < 4; ++mi) {
            f32x4 v;
#pragma unroll
            for (int rg = 0; rg < 4; ++rg)
                v[rg] = acc[mi][nj][rg] + acc2[mi][nj][rg] * LO_INV + bias;
            *(f32x4*)&orow[mi * 16] = v;
        }
    }
}

__global__ void k_lossfin(const float* __restrict__ lossp, float* __restrict__ out) {
    int gq = blockIdx.x;   // 16 blocks
    float s = 0.f;
    for (int u = threadIdx.x; u < 1024; u += 256) s += lossp[(size_t)gq * 1024 + u];
    int wave = threadIdx.x >> 6, lane = threadIdx.x & 63;
#pragma unroll
    for (int m = 1; m < 64; m <<= 1) s += __shfl_xor(s, m);
    __shared__ float sh[4];
    if (lane == 0) sh[wave] = s;
    __syncthreads();
    if (threadIdx.x == 0)
        out[gq] = (sh[0] + sh[1] + sh[2] + sh[3]) * (1.f / (8.f * 4096.f * 256.f));
}

extern "C" void kernel_launch(void* const* d_in, const int* in_sizes, int n_in,
                              void* d_out, int out_size, void* d_ws, size_t ws_size,
                              hipStream_t stream) {
    (void)in_sizes; (void)n_in; (void)out_size; (void)ws_size;
    const float* x     = (const float*)d_in[0];
    const float* cew   = (const float*)d_in[1];
    const float* ceb   = (const float*)d_in[2];
    const float* prew  = (const float*)d_in[3];
    const float* preb  = (const float*)d_in[4];
    const float* cb    = (const float*)d_in[5];
    const float* postw = (const float*)d_in[6];
    const float* postb = (const float*)d_in[7];
    // d_in[8], d_in[9]: conv_dec weights — result discarded by reference, skip.

    float* out = (float*)d_out;
    float* ws  = (float*)d_ws;
    float* wft   = ws + OFF_WFT;
    float* bf    = ws + OFF_BF;
    float* c2    = ws + OFF_C2;
    f16*   qh    = (f16*)(ws + OFF_QH);
    f16*   ql    = qh + 16777216;
    float* candd = ws + OFF_CANDD;
    int*   candi = (int*)(ws + OFF_CANDI);
    float* lossp = ws + OFF_LOSSP;
    f16*   pwh   = (f16*)(ws + OFF_PWH);
    f16*   pwl   = pwh + 262144;
    // fp32 residual state lives in the d_out q-region (dead until k_post overwrites)
    float* hres = out;

    k_fuse_w<<<192, 256, 0, stream>>>(cew, prew, wft);
    k_bias<<<2, 256, 0, stream>>>(prew, preb, ceb, bf);
    k_c2<<<4096, 256, 0, stream>>>(cb, c2);
    k_split_pw<<<256, 256, 0, stream>>>(postw, pwh, pwl);
    k_conv<<<4096, 256, 0, stream>>>(x, wft, bf, hres);
    for (int q = 0; q < 8; ++q) {
        for (int g = 0; g < 2; ++g) {
            k_dots<<<2048, 256, 0, stream>>>(hres, cb, c2, candd, candi, q, g);
            k_fin<<<1024, 256, 0, stream>>>(hres, cb, candd, candi, lossp,
                                            out + IDX_OFF, q, g);
        }
    }
    k_qsum2<<<16384, 256, 0, stream>>>(out + IDX_OFF, cb, qh, ql);
    k_post_mfma<<<1024, 256, 0, stream>>>(qh, ql, pwh, pwl, postb, out);
    k_lossfin<<<16, 256, 0, stream>>>(lossp, out + LOSS_OFF);
}

// Round 9
// 4545.546 us; speedup vs baseline: 1.0833x; 1.0509x over previous
//
#include <hip/hip_runtime.h>
#include <cstdint>
#include <cstddef>

// Problem constants
#define BB     8
#define DIMC   512
#define LL     4096
#define POSN   (BB*LL)        // 32768
#define NG     2
#define NQ     8
#define CS     1024
#define DG     256

// d_out layout (floats): q [8*512*4096] | indices [2*8*4096*8] | losses [16]
#define Q_OFF    0
#define IDX_OFF  16777216
#define LOSS_OFF 17301504

// d_ws layout (floats)
#define OFF_WFT   0               // [1536][512]
#define OFF_BF    786432          // [512]
#define OFF_C2    786944          // [16][1024]
#define OFF_QH    803328          // qh+ql: 2 x 16777216 f16 = 16777216 floats
#define OFF_CANDD 17580544        // [2][32768][8] float = 524288
#define OFF_CANDI 18104832        // [2][32768][8] int   = 524288
#define OFF_LOSSP 18629120        // [16][1024]
#define OFF_PWH   18645504        // pwh+pwl: 2 x 262144 f16 = 262144 floats
// total 18907648 floats = 75.6 MB

typedef _Float16 f16;
typedef _Float16 f16x8 __attribute__((ext_vector_type(8)));
typedef _Float16 f16x4 __attribute__((ext_vector_type(4)));
typedef float f32x4 __attribute__((ext_vector_type(4)));

#define LO_SCALE      1024.f
#define LO_INV        (1.f/1024.f)
#define F16_MIN_NORM  6.103515625e-05f

struct f16pair { f16 h, l; };

// flush-proof fp16 hi/lo split (used ONLY on the post-linear path, never on
// anything that feeds the VQ argmin)
__device__ __forceinline__ f16pair split1(float v) {
    f16 hv = (f16)v;
    float hf = (float)hv;
    if (__builtin_fabsf(hf) < F16_MIN_NORM) { hv = (f16)0.f; hf = 0.f; }
    f16pair p;
    p.h = hv;
    p.l = (f16)((v - hf) * LO_SCALE);
    return p;
}

__device__ __forceinline__ void gload16(const void* g, void* l) {
    __builtin_amdgcn_global_load_lds(
        (const __attribute__((address_space(1))) void*)g,
        (__attribute__((address_space(3))) void*)l, 16, 0, 0);
}

// ---------------------------------------------------------------------------
// Fuse conv_enc weights with pre_w:  Wf_t[ik][dd] = sum_j cw[j][i][k]*prew[dd][j]
__global__ __launch_bounds__(256) void k_fuse_w(const float* __restrict__ cw,
                                               const float* __restrict__ prew,
                                               float* __restrict__ wft) {
    __shared__ __align__(16) float As[16][68];  // As[k][ik]
    __shared__ __align__(16) float Bs[16][68];  // Bs[k][dd]
    int bid = blockIdx.x;
    int mt = bid >> 3, nt = bid & 7;            // 24 x 8
    int m0 = mt * 64, n0 = nt * 64;
    int t = threadIdx.x, tx = t & 15, ty = t >> 4;
    float acc[4][4] = {};
    for (int k0 = 0; k0 < 512; k0 += 16) {
        for (int u = t; u < 16 * 64; u += 256) {
            int kk = u >> 6, mm = u & 63;
            As[kk][mm] = cw[(size_t)(k0 + kk) * 1536 + m0 + mm];
        }
        {
            int r = t >> 2, c4 = t & 3;
            float4 v = *(const float4*)&prew[(size_t)(n0 + r) * 512 + k0 + c4 * 4];
            Bs[c4 * 4 + 0][r] = v.x; Bs[c4 * 4 + 1][r] = v.y;
            Bs[c4 * 4 + 2][r] = v.z; Bs[c4 * 4 + 3][r] = v.w;
        }
        __syncthreads();
#pragma unroll
        for (int k = 0; k < 16; ++k) {
            float4 a = *(const float4*)&As[k][ty * 4];
            float4 b = *(const float4*)&Bs[k][tx * 4];
            float av[4] = {a.x, a.y, a.z, a.w}, bv[4] = {b.x, b.y, b.z, b.w};
#pragma unroll
            for (int i = 0; i < 4; ++i)
#pragma unroll
                for (int j = 0; j < 4; ++j) acc[i][j] += av[i] * bv[j];
        }
        __syncthreads();
    }
#pragma unroll
    for (int i = 0; i < 4; ++i) {
        float4 v = {acc[i][0], acc[i][1], acc[i][2], acc[i][3]};
        *(float4*)&wft[(size_t)(m0 + ty * 4 + i) * 512 + n0 + tx * 4] = v;
    }
}

// Fused bias: bf[dd] = preb[dd] + sum_j prew[dd][j]*ceb[j]
__global__ void k_bias(const float* __restrict__ prew, const float* __restrict__ preb,
                       const float* __restrict__ ceb, float* __restrict__ bf) {
    int dd = blockIdx.x * 256 + threadIdx.x;
    if (dd < 512) {
        float s = preb[dd];
        for (int j = 0; j < 512; ++j) s += prew[(size_t)dd * 512 + j] * ceb[j];
        bf[dd] = s;
    }
}

// c2[row] = sum_d cb[row][d]^2, row over [16][1024]
__global__ void k_c2(const float* __restrict__ cb, float* __restrict__ c2) {
    int wave = threadIdx.x >> 6, lane = threadIdx.x & 63;
    int row = blockIdx.x * 4 + wave;  // < 16384
    const float* r = cb + (size_t)row * 256;
    float4 v = *(const float4*)&r[lane * 4];
    float s = v.x * v.x + v.y * v.y + v.z * v.z + v.w * v.w;
#pragma unroll
    for (int m = 1; m < 64; m <<= 1) s += __shfl_xor(s, m);
    if (lane == 0) c2[row] = s;
}

// split post_w fp32 -> fp16 hi + scaled fp16 lo (post-linear operands only)
__global__ void k_split_pw(const float* __restrict__ pw, f16* __restrict__ ph,
                           f16* __restrict__ pl) {
    size_t i = ((size_t)blockIdx.x * 256 + threadIdx.x) * 4;
    float4 v = *(const float4*)&pw[i];
    f16x4 hv, lv;
    f16pair p0 = split1(v.x), p1 = split1(v.y), p2 = split1(v.z), p3 = split1(v.w);
    hv.x = p0.h; lv.x = p0.l;
    hv.y = p1.h; lv.y = p1.l;
    hv.z = p2.h; lv.z = p2.l;
    hv.w = p3.h; lv.w = p3.l;
    *(f16x4*)&ph[i] = hv;
    *(f16x4*)&pl[i] = lv;
}

// Fused conv1d(k=3) + pre-linear: BASELINE-VERBATIM fp32 (feeds the argmin)
__global__ __launch_bounds__(256) void k_conv(const float* __restrict__ x,
                                              const float* __restrict__ wft,
                                              const float* __restrict__ bf,
                                              float* __restrict__ h) {
    int bid = blockIdx.x;              // 4096 = dt(8) * b(8) * lt(64)
    int dt = bid >> 9;
    int rem = bid & 511;
    int bb = rem >> 6, lt = rem & 63;
    int l0 = lt * 64, d0 = dt * 64;
    int t = threadIdx.x, tx = t & 15, ty = t >> 4;
    __shared__ float Xs[8][68];
    __shared__ __align__(16) float Ws[24][64];
    float acc[4][4] = {};
    const float* xb = x + (size_t)bb * 512 * 4096;
    for (int i0 = 0; i0 < 512; i0 += 8) {
        for (int u = t; u < 8 * 66; u += 256) {
            int ii = u / 66, c = u % 66;
            int gl = l0 + c - 1;
            Xs[ii][c] = (gl >= 0 && gl < 4096) ? xb[(size_t)(i0 + ii) * 4096 + gl] : 0.f;
        }
        for (int u = t; u < 24 * 64; u += 256) {
            int r = u >> 6, c = u & 63;
            Ws[r][c] = wft[(size_t)(i0 * 3 + r) * 512 + d0 + c];
        }
        __syncthreads();
#pragma unroll
        for (int ii = 0; ii < 8; ++ii) {
            float a[6];
#pragma unroll
            for (int j = 0; j < 6; ++j) a[j] = Xs[ii][ty * 4 + j];
#pragma unroll
            for (int k = 0; k < 3; ++k) {
                float4 b = *(const float4*)&Ws[ii * 3 + k][tx * 4];
                float bv[4] = {b.x, b.y, b.z, b.w};
#pragma unroll
                for (int jl = 0; jl < 4; ++jl)
#pragma unroll
                    for (int jd = 0; jd < 4; ++jd) acc[jl][jd] += a[jl + k] * bv[jd];
            }
        }
        __syncthreads();
    }
    int posb = bb * 4096 + l0 + ty * 4;
    const float4 bias = *(const float4*)&bf[d0 + tx * 4];
#pragma unroll
    for (int jl = 0; jl < 4; ++jl) {
        float4 v = {acc[jl][0] + bias.x, acc[jl][1] + bias.y,
                    acc[jl][2] + bias.z, acc[jl][3] + bias.w};
        *(float4*)&h[(size_t)(posb + jl) * 512 + d0 + tx * 4] = v;
    }
}

// dots GEMM + per-tile argmin: bit-exact fmac order (k ascending per dot),
// restructured: double-buffered LDS (1 barrier/chunk), register prefetch of the
// next chunk's global loads, epilogue arrays aliased onto dead buf-0 LDS,
// both groups merged into one dispatch. Grid 4096 = g(2) x mt(256) x nt(8).
__global__ __launch_bounds__(256) void k_dots(const float* __restrict__ hres,
                                              const float* __restrict__ cb,
                                              const float* __restrict__ c2,
                                              float* __restrict__ candd,
                                              int* __restrict__ candi,
                                              int q) {
    // layout: A[buf][k][132] at buf*2112, B[buf][k][132] at 4224+buf*2112
    __shared__ __align__(16) float smem[8448];   // 33 KB
    int bid = blockIdx.x;
    int g = bid >> 11;
    int r = bid & 2047;
    int mt = r >> 3, nt = r & 7;
    int p0 = mt * 128, n0 = nt * 128;
    int t = threadIdx.x, pt = t & 15, ct = t >> 4;
    const float* cbq = cb + (size_t)(q * 2 + g) * 1024 * 256;
    const float* c2q = c2 + (q * 2 + g) * 1024;
    const float* pA = hres + (size_t)p0 * 512 + (size_t)g * 256;  // row stride 512
    const float* pB = cbq + (size_t)n0 * 256;                     // row stride 256
    int r0 = t >> 2, c4 = t & 3;
    int r1 = r0 + 64;
    float acc[8][8] = {};
    // prefetch chunk 0
    float4 va0 = *(const float4*)&pA[(size_t)r0 * 512 + c4 * 4];
    float4 va1 = *(const float4*)&pA[(size_t)r1 * 512 + c4 * 4];
    float4 vb0 = *(const float4*)&pB[(size_t)r0 * 256 + c4 * 4];
    float4 vb1 = *(const float4*)&pB[(size_t)r1 * 256 + c4 * 4];
    for (int c = 0; c < 16; ++c) {
        int buf = c & 1;
        // transposed LDS writes (same element mapping as the verified kernel)
        float* wa = &smem[buf * 2112 + (c4 * 4) * 132];
        float* wb = wa + 4224;
        wa[r0] = va0.x; wa[132 + r0] = va0.y; wa[264 + r0] = va0.z; wa[396 + r0] = va0.w;
        wa[r1] = va1.x; wa[132 + r1] = va1.y; wa[264 + r1] = va1.z; wa[396 + r1] = va1.w;
        wb[r0] = vb0.x; wb[132 + r0] = vb0.y; wb[264 + r0] = vb0.z; wb[396 + r0] = vb0.w;
        wb[r1] = vb1.x; wb[132 + r1] = vb1.y; wb[264 + r1] = vb1.z; wb[396 + r1] = vb1.w;
        // issue next chunk's loads; latency hides under barrier + compute
        if (c < 15) {
            int ko = (c + 1) * 16;
            va0 = *(const float4*)&pA[(size_t)r0 * 512 + ko + c4 * 4];
            va1 = *(const float4*)&pA[(size_t)r1 * 512 + ko + c4 * 4];
            vb0 = *(const float4*)&pB[(size_t)r0 * 256 + ko + c4 * 4];
            vb1 = *(const float4*)&pB[(size_t)r1 * 256 + ko + c4 * 4];
        }
        __syncthreads();
        // single barrier per chunk is safe: iter c+1 writes buf^1, whose last
        // readers (compute of iter c-1) all passed this barrier already.
        const float* Ab = &smem[buf * 2112];
        const float* Bb = Ab + 4224;
#pragma unroll
        for (int k = 0; k < 16; ++k) {
            float4 a0 = *(const float4*)&Ab[k * 132 + pt * 8];
            float4 a1 = *(const float4*)&Ab[k * 132 + pt * 8 + 4];
            float4 b0 = *(const float4*)&Bb[k * 132 + ct * 8];
            float4 b1 = *(const float4*)&Bb[k * 132 + ct * 8 + 4];
            float av[8] = {a0.x, a0.y, a0.z, a0.w, a1.x, a1.y, a1.z, a1.w};
            float bv[8] = {b0.x, b0.y, b0.z, b0.w, b1.x, b1.y, b1.z, b1.w};
#pragma unroll
            for (int i = 0; i < 8; ++i)
#pragma unroll
                for (int j = 0; j < 8; ++j) acc[i][j] += av[i] * bv[j];
        }
    }
    // epilogue: per-thread argmin over its 8 codes (ascending c; strict <).
    // Dd overlays B buf0 (dead after chunk 14), Di overlays A buf0.
    float* Dd = smem + 4224;
    int*   Di = (int*)smem;
#pragma unroll
    for (int i = 0; i < 8; ++i) {
        float bd = 1e30f; int bi = 0x7fffffff;
#pragma unroll
        for (int j = 0; j < 8; ++j) {
            int cc = n0 + ct * 8 + j;
            float d = c2q[cc] - 2.f * acc[i][j];
            if (d < bd) { bd = d; bi = cc; }
        }
        Dd[ct * 128 + pt * 8 + i] = bd;
        Di[ct * 128 + pt * 8 + i] = bi;
    }
    __syncthreads();
    if (t < 128) {
        float bd = Dd[t]; int bi = Di[t];
#pragma unroll
        for (int j = 1; j < 16; ++j) {
            float d = Dd[j * 128 + t]; int i2 = Di[j * 128 + t];
            if (d < bd || (d == bd && i2 < bi)) { bd = d; bi = i2; }
        }
        candd[((size_t)g * 32768 + p0 + t) * 8 + nt] = bd;
        candi[((size_t)g * 32768 + p0 + t) * 8 + nt] = bi;
    }
}

// finalize one VQ step (both groups): BASELINE-VERBATIM selection/update
__global__ __launch_bounds__(256) void k_fin(float* __restrict__ hres,
                                             const float* __restrict__ cb,
                                             const float* __restrict__ candd,
                                             const int* __restrict__ candi,
                                             float* __restrict__ lossp,
                                             float* __restrict__ idx_out,
                                             int q) {
    int t = threadIdx.x, wave = t >> 6, lane = t & 63;
    int g = blockIdx.x >> 10, blk = blockIdx.x & 1023;
    const float* cbq = cb + (size_t)(q * 2 + g) * 1024 * 256;
    float lsum = 0.f;
    int pbase = blk * 32 + wave * 8;   // 32 pos/block
    for (int i = 0; i < 8; ++i) {
        int pos = pbase + i;
        size_t cbase = ((size_t)g * 32768 + pos) * 8;
        float bd; int bi;
        if (lane < 8) { bd = candd[cbase + lane]; bi = candi[cbase + lane]; }
        else          { bd = 1e30f; bi = 0x7fffffff; }
#pragma unroll
        for (int m = 1; m < 8; m <<= 1) {
            float d2 = __shfl_xor(bd, m);
            int   i2 = __shfl_xor(bi, m);
            if (d2 < bd || (d2 == bd && i2 < bi)) { bd = d2; bi = i2; }
        }
        int idx = __shfl(bi, 0);
        float4 cv = *(const float4*)&cbq[(size_t)idx * 256 + lane * 4];
        size_t ro = (size_t)pos * 512 + g * 256 + lane * 4;
        float4 rv = *(const float4*)&hres[ro];
        float4 rn = {rv.x - cv.x, rv.y - cv.y, rv.z - cv.z, rv.w - cv.w};
        *(float4*)&hres[ro] = rn;
        lsum += rn.x * rn.x + rn.y * rn.y + rn.z * rn.z + rn.w * rn.w;
        if (lane == 0)
            idx_out[(size_t)(g * 32768 + pos) * 8 + q] = (float)idx;
    }
#pragma unroll
    for (int m = 1; m < 64; m <<= 1) lsum += __shfl_xor(lsum, m);
    __shared__ float ls[4];
    if (lane == 0) ls[wave] = lsum;
    __syncthreads();
    if (t == 0) lossp[(size_t)(g * 8 + q) * 1024 + blk] = ls[0] + ls[1] + ls[2] + ls[3];
}

// qout[pos][g*256..] = sum_q cb[q][g][idx[q]]; written as f16 hi/lo split for k_post
__global__ __launch_bounds__(256) void k_qsum2(const float* __restrict__ idxf,
                                               const float* __restrict__ cb,
                                               f16* __restrict__ qh,
                                               f16* __restrict__ ql) {
    int t = threadIdx.x, w = t >> 6, lane = t & 63;
    int pair = blockIdx.x * 4 + w;       // 65536 pairs
    int g = pair & 1, pos = pair >> 1;
    const float* ip = idxf + ((size_t)g * 32768 + pos) * 8;
    float4 s = {0.f, 0.f, 0.f, 0.f};
    for (int qq = 0; qq < 8; ++qq) {
        int ii = (int)ip[qq];
        const float* rowp = cb + ((size_t)(qq * 2 + g) * 1024 + ii) * 256;
        float4 v = *(const float4*)&rowp[lane * 4];
        s.x += v.x; s.y += v.y; s.z += v.z; s.w += v.w;
    }
    f16x4 hv, lv;
    f16pair p0 = split1(s.x), p1 = split1(s.y), p2 = split1(s.z), p3 = split1(s.w);
    hv.x = p0.h; lv.x = p0.l;
    hv.y = p1.h; lv.y = p1.l;
    hv.z = p2.h; lv.z = p2.l;
    hv.w = p3.h; lv.w = p3.l;
    size_t o = (size_t)pos * 512 + g * 256 + lane * 4;
    *(f16x4*)&qh[o] = hv;
    *(f16x4*)&ql[o] = lv;
}

// post-linear via MFMA fp16x3 (output tolerance ~1e-2; fp16x3 error ~1e-7).
// Grid 1024 = mt(256) x nt(4). Tile 128 pos x 128 dd, K=512 in chunks of 32.
__global__ __launch_bounds__(256) void k_post_mfma(const f16* __restrict__ qh,
                                                   const f16* __restrict__ ql,
                                                   const f16* __restrict__ pwh,
                                                   const f16* __restrict__ pwl,
                                                   const float* __restrict__ pb,
                                                   float* __restrict__ out) {
    __shared__ __align__(16) f16 Ah[4096], Al[4096], Bh[4096], Bl[4096];
    int bid = blockIdx.x;
    int mt = bid >> 2, nt = bid & 3;
    int p0 = mt << 7, d0 = nt << 7;
    int t = threadIdx.x, w = t >> 6, lane = t & 63;
    int wm = (w >> 1) * 64, wn = (w & 1) * 64;
    const f16* gA;
    f16* lA;
    {
        const f16* a0 = qh + (size_t)p0 * 512;
        const f16* a1 = ql + (size_t)p0 * 512;
        const f16* b0 = pwh + (size_t)d0 * 512;
        const f16* b1 = pwl + (size_t)d0 * 512;
        gA = (w == 0) ? a0 : (w == 1) ? a1 : (w == 2) ? b0 : b1;
        lA = (w == 0) ? Ah : (w == 1) ? Al : (w == 2) ? Bh : Bl;
    }
    f32x4 acc[4][4] = {};    // hi.hi
    f32x4 acc2[4][4] = {};   // hi.lo' + lo'.hi  (1024x true value)
    int lr = lane & 15, kq = lane >> 4;
    for (int k0 = 0; k0 < 512; k0 += 32) {
#pragma unroll
        for (int u = 0; u < 8; ++u) {
            int kb = u >> 1, hf = u & 1;
            gload16(gA + (size_t)(hf * 64 + lane) * 512 + k0 + kb * 8,
                    lA + kb * 1024 + hf * 512);
        }
        __syncthreads();
        f16x8 a_h[4], a_l[4], b_h[4], b_l[4];
#pragma unroll
        for (int i = 0; i < 4; ++i) {
            int ao = kq * 1024 + (wm + i * 16 + lr) * 8;
            int bo = kq * 1024 + (wn + i * 16 + lr) * 8;
            a_h[i] = *(const f16x8*)&Ah[ao];
            a_l[i] = *(const f16x8*)&Al[ao];
            b_h[i] = *(const f16x8*)&Bh[bo];
            b_l[i] = *(const f16x8*)&Bl[bo];
        }
#pragma unroll
        for (int i = 0; i < 4; ++i)
#pragma unroll
            for (int j = 0; j < 4; ++j) {
                acc[i][j]  = __builtin_amdgcn_mfma_f32_16x16x32_f16(a_h[i], b_h[j], acc[i][j], 0, 0, 0);
                acc2[i][j] = __builtin_amdgcn_mfma_f32_16x16x32_f16(a_h[i], b_l[j], acc2[i][j], 0, 0, 0);
                acc2[i][j] = __builtin_amdgcn_mfma_f32_16x16x32_f16(a_l[i], b_h[j], acc2[i][j], 0, 0, 0);
            }
        __syncthreads();
    }
    // C/D: col = lane&15 (dd), row = (lane>>4)*4 + rg (pos). Store f32x4 over rg.
    int bb = p0 >> 12, l0 = p0 & 4095;
#pragma unroll
    for (int nj = 0; nj < 4; ++nj) {
        int dd = d0 + wn + nj * 16 + lr;
        float bias = pb[dd];
        float* orow = out + ((size_t)bb * 512 + dd) * 4096 + l0 + wm + kq * 4;
#pragma unroll
        for (int mi = 0; mi < 4; ++mi) {
            f32x4 v;
#pragma unroll
            for (int rg = 0; rg < 4; ++rg)
                v[rg] = acc[mi][nj][rg] + acc2[mi][nj][rg] * LO_INV + bias;
            *(f32x4*)&orow[mi * 16] = v;
        }
    }
}

__global__ void k_lossfin(const float* __restrict__ lossp, float* __restrict__ out) {
    int gq = blockIdx.x;   // 16 blocks
    float s = 0.f;
    for (int u = threadIdx.x; u < 1024; u += 256) s += lossp[(size_t)gq * 1024 + u];
    int wave = threadIdx.x >> 6, lane = threadIdx.x & 63;
#pragma unroll
    for (int m = 1; m < 64; m <<= 1) s += __shfl_xor(s, m);
    __shared__ float sh[4];
    if (lane == 0) sh[wave] = s;
    __syncthreads();
    if (threadIdx.x == 0)
        out[gq] = (sh[0] + sh[1] + sh[2] + sh[3]) * (1.f / (8.f * 4096.f * 256.f));
}

extern "C" void kernel_launch(void* const* d_in, const int* in_sizes, int n_in,
                              void* d_out, int out_size, void* d_ws, size_t ws_size,
                              hipStream_t stream) {
    (void)in_sizes; (void)n_in; (void)out_size; (void)ws_size;
    const float* x     = (const float*)d_in[0];
    const float* cew   = (const float*)d_in[1];
    const float* ceb   = (const float*)d_in[2];
    const float* prew  = (const float*)d_in[3];
    const float* preb  = (const float*)d_in[4];
    const float* cb    = (const float*)d_in[5];
    const float* postw = (const float*)d_in[6];
    const float* postb = (const float*)d_in[7];
    // d_in[8], d_in[9]: conv_dec weights — result discarded by reference, skip.

    float* out = (float*)d_out;
    float* ws  = (float*)d_ws;
    float* wft   = ws + OFF_WFT;
    float* bf    = ws + OFF_BF;
    float* c2    = ws + OFF_C2;
    f16*   qh    = (f16*)(ws + OFF_QH);
    f16*   ql    = qh + 16777216;
    float* candd = ws + OFF_CANDD;
    int*   candi = (int*)(ws + OFF_CANDI);
    float* lossp = ws + OFF_LOSSP;
    f16*   pwh   = (f16*)(ws + OFF_PWH);
    f16*   pwl   = pwh + 262144;
    // fp32 residual state lives in the d_out q-region (dead until k_post overwrites)
    float* hres = out;

    k_fuse_w<<<192, 256, 0, stream>>>(cew, prew, wft);
    k_bias<<<2, 256, 0, stream>>>(prew, preb, ceb, bf);
    k_c2<<<4096, 256, 0, stream>>>(cb, c2);
    k_split_pw<<<256, 256, 0, stream>>>(postw, pwh, pwl);
    k_conv<<<4096, 256, 0, stream>>>(x, wft, bf, hres);
    for (int q = 0; q < 8; ++q) {
        k_dots<<<4096, 256, 0, stream>>>(hres, cb, c2, candd, candi, q);
        k_fin<<<2048, 256, 0, stream>>>(hres, cb, candd, candi, lossp,
                                        out + IDX_OFF, q);
    }
    k_qsum2<<<16384, 256, 0, stream>>>(out + IDX_OFF, cb, qh, ql);
    k_post_mfma<<<1024, 256, 0, stream>>>(qh, ql, pwh, pwl, postb, out);
    k_lossfin<<<16, 256, 0, stream>>>(lossp, out + LOSS_OFF);
}